// Round 3
// baseline (66739.148 us; speedup 1.0000x reference)
//
#include <hip/hip_runtime.h>

#define T_OBS 512
#define HID   48

typedef float vf4 __attribute__((ext_vector_type(4)));

// sigmoid(x) = 1/(1+2^(-x*log2 e)) ; tanh(x) = 1 - 2/(1+2^(2x*log2 e))
__device__ __forceinline__ float sigm(float v) {
    return __builtin_amdgcn_rcpf(1.f + __builtin_amdgcn_exp2f(-1.44269504089f * v));
}
__device__ __forceinline__ float tanh_f(float v) {
    return 1.f - 2.f * __builtin_amdgcn_rcpf(1.f + __builtin_amdgcn_exp2f(2.88539008178f * v));
}

// 256 threads = 4 waves. Waves {0,1} serve batches bb0..bb0+7 (group 0),
// waves {2,3} the next 8 (group 1). Within a group, the two waves split the
// reduction dimension k. Each lane owns 3 gate-rows (192 rows / 64 lanes);
// weights live in VGPRs (~216/lane), loaded once. LDS is used only for the
// per-step partial-gate exchange, the h broadcast buffer, and the fed-back input.
__global__ __launch_bounds__(256, 1) void lstm2_kernel(
    const float* __restrict__ x,
    const float* __restrict__ Wih0, const float* __restrict__ Whh0,
    const float* __restrict__ bih0, const float* __restrict__ bhh0,
    const float* __restrict__ Wih1, const float* __restrict__ Whh1,
    const float* __restrict__ bih1, const float* __restrict__ bhh1,
    const float* __restrict__ Wlin, const float* __restrict__ blin,
    const int* __restrict__ fut,
    float* __restrict__ out)
{
    __shared__ __attribute__((aligned(16))) float s_pg[2][2][1536]; // [grp][half][row*8+b]
    __shared__ __attribute__((aligned(16))) float s_h[2][768];      // [grp][(L*48+u)*8+b]
    __shared__ __attribute__((aligned(16))) float s_inp[2][8];

    const int tid  = threadIdx.x;
    const int wave = tid >> 6, lane = tid & 63;
    const int grp  = wave >> 1;      // batch pair-group
    const int half = wave & 1;       // k-split half
    const int r0   = lane * 3;       // first of this lane's 3 gate-rows

    // zero h state
    for (int i = tid; i < 2 * 768; i += 256) (&s_h[0][0])[i] = 0.f;

    // ---- one-time: weights into registers ----
    float w0[3][24];    // Whh0[r0+i][half*24 + k]
    float w1[3][48];    // half==0: Wih1[r][k] (vs h0_new) ; half==1: Whh1[r][k] (vs h1_old)
    float wih0r[3], b0r[3], b1r[3];
    const float* W1src = half ? Whh1 : Wih1;
    #pragma unroll
    for (int i = 0; i < 3; ++i) {
        const int r = r0 + i;
        #pragma unroll
        for (int kk = 0; kk < 6; ++kk) {
            const vf4 v = *(const vf4*)(Whh0 + r * 48 + half * 24 + kk * 4);
            w0[i][kk*4+0] = v[0]; w0[i][kk*4+1] = v[1];
            w0[i][kk*4+2] = v[2]; w0[i][kk*4+3] = v[3];
        }
        #pragma unroll
        for (int kk = 0; kk < 12; ++kk) {
            const vf4 v = *(const vf4*)(W1src + r * 48 + kk * 4);
            w1[i][kk*4+0] = v[0]; w1[i][kk*4+1] = v[1];
            w1[i][kk*4+2] = v[2]; w1[i][kk*4+3] = v[3];
        }
        wih0r[i] = Wih0[r];
        b0r[i]   = bih0[r] + bhh0[r];
        b1r[i]   = bih1[r] + bhh1[r];
    }
    // head weights: lane = u_idx*8 + bh ; lane handles units u_idx*6..+5, batch bh
    const int u_idx = lane >> 3, bh = lane & 7;
    float wl[6];
    #pragma unroll
    for (int j = 0; j < 6; ++j) wl[j] = Wlin[u_idx * 6 + j];
    const float bl = blin[0];

    // c-state: thread tau = half*64+lane owns pairs p = tau*3..tau*3+2, p=(u,b)
    float c0s[3], c1s[3];
    int pbase[3];
    #pragma unroll
    for (int i = 0; i < 3; ++i) {
        c0s[i] = 0.f; c1s[i] = 0.f;
        pbase[i] = (half * 64 + lane) * 3 + i;   // == u*8 + b
    }

    const int F    = fut[0];
    const int Ttot = T_OBS + F;
    const int bb0  = blockIdx.x * 16 + grp * 8;

    float* pgw        = &s_pg[grp][half][0];
    const float* pgA  = &s_pg[grp][0][0];
    const float* pgB  = &s_pg[grp][1][0];
    float* hbuf       = &s_h[grp][0];

    // prefetch x(t=0)
    float xc[8];
    if (half == 0) {
        #pragma unroll
        for (int b = 0; b < 8; ++b) xc[b] = x[(bb0 + b) * T_OBS];
    }

    __syncthreads();

    for (int t = 0; t < Ttot; ++t) {
        if (t >= T_OBS) __syncthreads();        // uniform branch: protect s_inp
        vf4 inA, inB;
        if (t < T_OBS) {
            if (half == 0) {
                inA[0]=xc[0]; inA[1]=xc[1]; inA[2]=xc[2]; inA[3]=xc[3];
                inB[0]=xc[4]; inB[1]=xc[5]; inB[2]=xc[6]; inB[3]=xc[7];
            }
        } else {
            inA = *(const vf4*)&s_inp[grp][0];
            inB = *(const vf4*)&s_inp[grp][4];
        }

        // ---------- P1: layer-0 partial gates ----------
        vf4 aA[3], aB[3];
        #pragma unroll
        for (int i = 0; i < 3; ++i) {
            if (half == 0) { aA[i] = b0r[i] + wih0r[i] * inA; aB[i] = b0r[i] + wih0r[i] * inB; }
            else           { aA[i] = (vf4)0.f;                aB[i] = (vf4)0.f; }
        }
        {
            const float* hsrc = hbuf + half * 24 * 8;   // h0 rows, this wave's k-half
            #pragma unroll
            for (int k = 0; k < 24; ++k) {
                const vf4 hA = *(const vf4*)(hsrc + k * 8);
                const vf4 hB = *(const vf4*)(hsrc + k * 8 + 4);
                #pragma unroll
                for (int i = 0; i < 3; ++i) {
                    aA[i] = w0[i][k] * hA + aA[i];
                    aB[i] = w0[i][k] * hB + aB[i];
                }
            }
        }
        #pragma unroll
        for (int i = 0; i < 3; ++i) {
            *(vf4*)(pgw + (r0 + i) * 8)     = aA[i];
            *(vf4*)(pgw + (r0 + i) * 8 + 4) = aB[i];
        }
        __syncthreads();                         // B1

        // ---------- P2: layer-0 combine (c0, h0) ----------
        #pragma unroll
        for (int i = 0; i < 3; ++i) {
            const int bse = pbase[i];
            const float g0 = pgA[bse]        + pgB[bse];
            const float g1 = pgA[bse + 384]  + pgB[bse + 384];
            const float g2 = pgA[bse + 768]  + pgB[bse + 768];
            const float g3 = pgA[bse + 1152] + pgB[bse + 1152];
            const float ig = sigm(g0), fg = sigm(g1);
            const float gg = tanh_f(g2), og = sigm(g3);
            c0s[i] = fg * c0s[i] + ig * gg;
            hbuf[bse] = og * tanh_f(c0s[i]);     // h0 region
        }
        __syncthreads();                         // B2

        // ---------- P3: layer-1 partial gates ----------
        float xn[8];
        if (half == 0 && t + 1 < T_OBS) {        // prefetch next x, hidden under k-loop
            #pragma unroll
            for (int b = 0; b < 8; ++b) xn[b] = x[(bb0 + b) * T_OBS + t + 1];
        }
        #pragma unroll
        for (int i = 0; i < 3; ++i) {
            if (half == 0) { aA[i] = (vf4)b1r[i]; aB[i] = (vf4)b1r[i]; }
            else           { aA[i] = (vf4)0.f;    aB[i] = (vf4)0.f; }
        }
        {
            const float* hsrc = hbuf + half * 384;  // half0: h0(new), half1: h1(old)
            #pragma unroll
            for (int k = 0; k < 48; ++k) {
                const vf4 hA = *(const vf4*)(hsrc + k * 8);
                const vf4 hB = *(const vf4*)(hsrc + k * 8 + 4);
                #pragma unroll
                for (int i = 0; i < 3; ++i) {
                    aA[i] = w1[i][k] * hA + aA[i];
                    aB[i] = w1[i][k] * hB + aB[i];
                }
            }
        }
        #pragma unroll
        for (int i = 0; i < 3; ++i) {
            *(vf4*)(pgw + (r0 + i) * 8)     = aA[i];
            *(vf4*)(pgw + (r0 + i) * 8 + 4) = aB[i];
        }
        __syncthreads();                         // B3

        // ---------- P4: layer-1 combine (c1, h1) ----------
        #pragma unroll
        for (int i = 0; i < 3; ++i) {
            const int bse = pbase[i];
            const float g0 = pgA[bse]        + pgB[bse];
            const float g1 = pgA[bse + 384]  + pgB[bse + 384];
            const float g2 = pgA[bse + 768]  + pgB[bse + 768];
            const float g3 = pgA[bse + 1152] + pgB[bse + 1152];
            const float ig = sigm(g0), fg = sigm(g1);
            const float gg = tanh_f(g2), og = sigm(g3);
            c1s[i] = fg * c1s[i] + ig * gg;
            hbuf[384 + bse] = og * tanh_f(c1s[i]);  // h1 region
        }
        __syncthreads();                         // B4

        // ---------- P5: linear head ----------
        float s = 0.f;
        #pragma unroll
        for (int j = 0; j < 6; ++j)
            s += wl[j] * hbuf[384 + (u_idx * 6 + j) * 8 + bh];
        s += __shfl_xor(s, 8);
        s += __shfl_xor(s, 16);
        s += __shfl_xor(s, 32);                  // reduce over u_idx; b preserved
        const float o = s + bl;
        if (half == 0 && lane < 8) {
            out[(bb0 + lane) * Ttot + t] = o;
            s_inp[grp][lane] = o;
        }
        if (half == 0 && t + 1 < T_OBS) {
            #pragma unroll
            for (int b = 0; b < 8; ++b) xc[b] = xn[b];
        }
    }
}

extern "C" void kernel_launch(void* const* d_in, const int* in_sizes, int n_in,
                              void* d_out, int out_size, void* d_ws, size_t ws_size,
                              hipStream_t stream) {
    const float* x    = (const float*)d_in[0];
    const float* Wih0 = (const float*)d_in[1];
    const float* Whh0 = (const float*)d_in[2];
    const float* bih0 = (const float*)d_in[3];
    const float* bhh0 = (const float*)d_in[4];
    const float* Wih1 = (const float*)d_in[5];
    const float* Whh1 = (const float*)d_in[6];
    const float* bih1 = (const float*)d_in[7];
    const float* bhh1 = (const float*)d_in[8];
    const float* Wlin = (const float*)d_in[9];
    const float* blin = (const float*)d_in[10];
    const int*   fut  = (const int*)d_in[11];
    float* out = (float*)d_out;

    const int B = in_sizes[0] / T_OBS;    // 4096
    const int grid = B / 16;              // 256 blocks -> 1 per CU
    lstm2_kernel<<<grid, 256, 0, stream>>>(
        x, Wih0, Whh0, bih0, bhh0, Wih1, Whh1, bih1, bhh1, Wlin, blin, fut, out);
}

// Round 4
// 25021.257 us; speedup vs baseline: 2.6673x; 2.6673x over previous
//
#include <hip/hip_runtime.h>

#define T_OBS 512
#define PGROW 20            // padded row stride (floats): conflict-free b128 access
#define PGW   (192*PGROW)   // per-wave partial-gate slab

typedef float vf4 __attribute__((ext_vector_type(4)));

// sigmoid(x) = 1/(1+2^(-x*log2 e)) ; tanh(x) = 1 - 2/(1+2^(2x*log2 e))
__device__ __forceinline__ float sigm(float v) {
    return __builtin_amdgcn_rcpf(1.f + __builtin_amdgcn_exp2f(-1.44269504089f * v));
}
__device__ __forceinline__ float tanh_f(float v) {
    return 1.f - 2.f * __builtin_amdgcn_rcpf(1.f + __builtin_amdgcn_exp2f(2.88539008178f * v));
}
__device__ __forceinline__ vf4 sigm4(vf4 v) {
    vf4 r; r[0]=sigm(v[0]); r[1]=sigm(v[1]); r[2]=sigm(v[2]); r[3]=sigm(v[3]); return r;
}
__device__ __forceinline__ vf4 tanh4(vf4 v) {
    vf4 r; r[0]=tanh_f(v[0]); r[1]=tanh_f(v[1]); r[2]=tanh_f(v[2]); r[3]=tanh_f(v[3]); return r;
}

// 256 threads = 4 waves; whole block cooperates on 16 batch elements.
// Wave w owns k-quarter of the reduction for ALL 192 gate-rows x 16 batches.
// Lane owns 3 gate-rows (r = u*4+q ordering); weights in VGPRs: 36+72 = 108/lane
// (stays under the 256 arch-VGPR cap -- Round 3's 216/lane spilled).
// Partial gates exchanged via padded LDS; combine threads (tid<192) own c-state.
__global__ __launch_bounds__(256, 1) void lstm2_kernel(
    const float* __restrict__ x,
    const float* __restrict__ Wih0, const float* __restrict__ Whh0,
    const float* __restrict__ bih0, const float* __restrict__ bhh0,
    const float* __restrict__ Wih1, const float* __restrict__ Whh1,
    const float* __restrict__ bih1, const float* __restrict__ bhh1,
    const float* __restrict__ Wlin, const float* __restrict__ blin,
    const int* __restrict__ fut,
    float* __restrict__ out)
{
    __shared__ __attribute__((aligned(16))) float s_pg[4*PGW];  // 61440 B
    __shared__ __attribute__((aligned(16))) float s_h[96*16];   // rows 0..47 h0, 48..95 h1

    const int tid  = threadIdx.x;
    const int w    = tid >> 6, lane = tid & 63;
    const int r0   = lane * 3;

    for (int i = tid; i < 96*16; i += 256) s_h[i] = 0.f;

    // ---- one-time: weight quarter into registers ----
    float w0[3][12];   // Whh0[rr][w*12+k]
    float w1[3][24];   // cat[Wih1,Whh1][rr][w*24+k]
    float wih0r[3];
    #pragma unroll
    for (int i = 0; i < 3; ++i) {
        const int r = r0 + i, u = r >> 2, q = r & 3;
        const int rr = q * 48 + u;            // PyTorch row (gate-major)
        #pragma unroll
        for (int k = 0; k < 12; ++k) w0[i][k] = Whh0[rr*48 + w*12 + k];
        #pragma unroll
        for (int k = 0; k < 24; ++k) {
            const int kk = w*24 + k;
            w1[i][k] = (kk < 48) ? Wih1[rr*48 + kk] : Whh1[rr*48 + kk - 48];
        }
        wih0r[i] = Wih0[rr];
    }

    // combine-role constants (threads 0..191): cell block (u_c, batch-quad bq)
    const int u_c = tid >> 2, bq = tid & 3;
    float bias0[4], bias1[4];
    if (tid < 192) {
        #pragma unroll
        for (int q = 0; q < 4; ++q) {
            bias0[q] = bih0[q*48 + u_c] + bhh0[q*48 + u_c];
            bias1[q] = bih1[q*48 + u_c] + bhh1[q*48 + u_c];
        }
    }
    // head constants (wave 0): lane = ug*16 + b16, units ug*12..+11
    const int ug = lane >> 4, b16 = lane & 15;
    float wl[12];
    #pragma unroll
    for (int j = 0; j < 12; ++j) wl[j] = Wlin[ug*12 + j];
    const float bl = blin[0];

    vf4 c0v = (vf4)0.f, c1v = (vf4)0.f;
    const int F    = fut[0];
    const int Ttot = T_OBS + F;
    const int bb0  = blockIdx.x * 16;

    float xcur = 0.f, oprev = 0.f;
    if (w == 0 && lane < 16) xcur = x[(bb0 + lane) * T_OBS];

    float* pgw = s_pg + w * PGW;
    __syncthreads();

    for (int t = 0; t < Ttot; ++t) {
        // ---- wave 0: build broadcast input (shuffles; no LDS, no race) ----
        vf4 inq[4];
        float xnext = 0.f;
        if (w == 0) {
            const float src = (t < T_OBS) ? xcur : oprev;
            #pragma unroll
            for (int qd = 0; qd < 4; ++qd)
                #pragma unroll
                for (int e = 0; e < 4; ++e)
                    inq[qd][e] = __shfl(src, qd*4 + e, 64);
            if (lane < 16 && t + 1 < T_OBS)
                xnext = x[(bb0 + lane) * T_OBS + t + 1];
        }

        // ---------- P1: layer-0 partial gates (k-quarter) ----------
        vf4 acc[3][4];
        #pragma unroll
        for (int i = 0; i < 3; ++i)
            #pragma unroll
            for (int qd = 0; qd < 4; ++qd)
                acc[i][qd] = (w == 0) ? wih0r[i] * inq[qd] : (vf4)0.f;
        {
            const float* hsrc = s_h + (w * 12) * 16;
            #pragma unroll
            for (int k = 0; k < 12; ++k) {
                vf4 hq[4];
                #pragma unroll
                for (int qd = 0; qd < 4; ++qd)
                    hq[qd] = *(const vf4*)(hsrc + k*16 + qd*4);   // uniform 16B broadcast
                #pragma unroll
                for (int i = 0; i < 3; ++i)
                    #pragma unroll
                    for (int qd = 0; qd < 4; ++qd)
                        acc[i][qd] = w0[i][k] * hq[qd] + acc[i][qd];
            }
        }
        #pragma unroll
        for (int i = 0; i < 3; ++i)
            #pragma unroll
            for (int qd = 0; qd < 4; ++qd)
                *(vf4*)(pgw + (r0 + i)*PGROW + qd*4) = acc[i][qd];
        __syncthreads();                                          // B1

        // ---------- P2: layer-0 combine ----------
        if (tid < 192) {
            vf4 g[4];
            #pragma unroll
            for (int q = 0; q < 4; ++q) {
                const float* p = s_pg + (u_c*4 + q)*PGROW + bq*4;
                vf4 s = *(const vf4*)p;
                s += *(const vf4*)(p + PGW);
                s += *(const vf4*)(p + 2*PGW);
                s += *(const vf4*)(p + 3*PGW);
                g[q] = s + bias0[q];
            }
            const vf4 ig = sigm4(g[0]), fg = sigm4(g[1]);
            const vf4 gg = tanh4(g[2]), og = sigm4(g[3]);
            c0v = fg * c0v + ig * gg;
            *(vf4*)(s_h + u_c*16 + bq*4) = og * tanh4(c0v);
        }
        __syncthreads();                                          // B2

        // ---------- P3: layer-1 partial gates (k-quarter over [h0;h1]) ----------
        #pragma unroll
        for (int i = 0; i < 3; ++i)
            #pragma unroll
            for (int qd = 0; qd < 4; ++qd)
                acc[i][qd] = (vf4)0.f;
        {
            const float* hsrc = s_h + (w * 24) * 16;
            #pragma unroll
            for (int k = 0; k < 24; ++k) {
                vf4 hq[4];
                #pragma unroll
                for (int qd = 0; qd < 4; ++qd)
                    hq[qd] = *(const vf4*)(hsrc + k*16 + qd*4);
                #pragma unroll
                for (int i = 0; i < 3; ++i)
                    #pragma unroll
                    for (int qd = 0; qd < 4; ++qd)
                        acc[i][qd] = w1[i][k] * hq[qd] + acc[i][qd];
            }
        }
        #pragma unroll
        for (int i = 0; i < 3; ++i)
            #pragma unroll
            for (int qd = 0; qd < 4; ++qd)
                *(vf4*)(pgw + (r0 + i)*PGROW + qd*4) = acc[i][qd];
        __syncthreads();                                          // B3

        // ---------- P4: layer-1 combine ----------
        if (tid < 192) {
            vf4 g[4];
            #pragma unroll
            for (int q = 0; q < 4; ++q) {
                const float* p = s_pg + (u_c*4 + q)*PGROW + bq*4;
                vf4 s = *(const vf4*)p;
                s += *(const vf4*)(p + PGW);
                s += *(const vf4*)(p + 2*PGW);
                s += *(const vf4*)(p + 3*PGW);
                g[q] = s + bias1[q];
            }
            const vf4 ig = sigm4(g[0]), fg = sigm4(g[1]);
            const vf4 gg = tanh4(g[2]), og = sigm4(g[3]);
            c1v = fg * c1v + ig * gg;
            *(vf4*)(s_h + (48 + u_c)*16 + bq*4) = og * tanh4(c1v);
        }
        __syncthreads();                                          // B4

        // ---------- P5: linear head (wave 0 only; feedback stays in-wave) ----------
        if (w == 0) {
            float s = 0.f;
            #pragma unroll
            for (int j = 0; j < 12; ++j)
                s += wl[j] * s_h[(48 + ug*12 + j)*16 + b16];
            s += __shfl_xor(s, 16, 64);
            s += __shfl_xor(s, 32, 64);          // lane (ug,b) -> full sum for batch b
            const float o = s + bl;
            if (lane < 16) out[(bb0 + lane) * Ttot + t] = o;
            oprev = o;
            xcur  = xnext;
        }
    }
}

extern "C" void kernel_launch(void* const* d_in, const int* in_sizes, int n_in,
                              void* d_out, int out_size, void* d_ws, size_t ws_size,
                              hipStream_t stream) {
    const float* x    = (const float*)d_in[0];
    const float* Wih0 = (const float*)d_in[1];
    const float* Whh0 = (const float*)d_in[2];
    const float* bih0 = (const float*)d_in[3];
    const float* bhh0 = (const float*)d_in[4];
    const float* Wih1 = (const float*)d_in[5];
    const float* Whh1 = (const float*)d_in[6];
    const float* bih1 = (const float*)d_in[7];
    const float* bhh1 = (const float*)d_in[8];
    const float* Wlin = (const float*)d_in[9];
    const float* blin = (const float*)d_in[10];
    const int*   fut  = (const int*)d_in[11];
    float* out = (float*)d_out;

    const int B = in_sizes[0] / T_OBS;    // 4096
    const int grid = B / 16;              // 256 blocks -> 1 per CU
    lstm2_kernel<<<grid, 256, 0, stream>>>(
        x, Wih0, Whh0, bih0, bhh0, Wih1, Whh1, bih1, bhh1, Wlin, blin, fut, out);
}

// Round 6
// 20575.580 us; speedup vs baseline: 3.2436x; 1.2161x over previous
//
#include <hip/hip_runtime.h>

#define T_OBS 512
#define PGROW 12            // padded row stride (floats): conflict-free b128 partial writes
#define PGW   (192*PGROW)   // per-wave partial-gate slab (8 batches/row + 4 pad)

typedef float vf4 __attribute__((ext_vector_type(4)));

// sigmoid(x) = 1/(1+2^(-x*log2 e)) ; tanh(x) = 1 - 2/(1+2^(2x*log2 e))
__device__ __forceinline__ float sigm(float v) {
    return __builtin_amdgcn_rcpf(1.f + __builtin_amdgcn_exp2f(-1.44269504089f * v));
}
__device__ __forceinline__ float tanh_f(float v) {
    return 1.f - 2.f * __builtin_amdgcn_rcpf(1.f + __builtin_amdgcn_exp2f(2.88539008178f * v));
}
__device__ __forceinline__ vf4 sigm4(vf4 v) {
    vf4 r; r[0]=sigm(v[0]); r[1]=sigm(v[1]); r[2]=sigm(v[2]); r[3]=sigm(v[3]); return r;
}
__device__ __forceinline__ vf4 tanh4(vf4 v) {
    vf4 r; r[0]=tanh_f(v[0]); r[1]=tanh_f(v[1]); r[2]=tanh_f(v[2]); r[3]=tanh_f(v[3]); return r;
}

// 256 threads = 4 waves; block cooperates on 8 batch elements (512 blocks -> 2/CU).
// Wave w owns k-quarter of the reduction for ALL 192 gate-rows x 8 batches.
// Lane owns 3 gate-rows; weights in VGPRs: 36+72+3 = 111/lane; total live ~190
// (Round 4's 16-batch version hit the 256 arch-VGPR cap and spilled weights).
__global__ __launch_bounds__(256, 1) void lstm2_kernel(
    const float* __restrict__ x,
    const float* __restrict__ Wih0, const float* __restrict__ Whh0,
    const float* __restrict__ bih0, const float* __restrict__ bhh0,
    const float* __restrict__ Wih1, const float* __restrict__ Whh1,
    const float* __restrict__ bih1, const float* __restrict__ bhh1,
    const float* __restrict__ Wlin, const float* __restrict__ blin,
    const int* __restrict__ fut,
    float* __restrict__ out)
{
    __shared__ __attribute__((aligned(16))) float s_pg[4*PGW];  // 36864 B
    __shared__ __attribute__((aligned(16))) float s_h[96*8];    // rows 0..47 h0, 48..95 h1

    const int tid  = threadIdx.x;
    const int w    = tid >> 6, lane = tid & 63;
    const int r0   = lane * 3;

    for (int i = tid; i < 96*8; i += 256) s_h[i] = 0.f;

    // ---- one-time: weight quarter into registers ----
    float w0[3][12];   // Whh0[rr][w*12+k]
    float w1[3][24];   // cat[Wih1,Whh1][rr][w*24+k]
    float wih0r[3];
    #pragma unroll
    for (int i = 0; i < 3; ++i) {
        const int r = r0 + i, u = r >> 2, q = r & 3;
        const int rr = q * 48 + u;            // PyTorch row (gate-major)
        #pragma unroll
        for (int k = 0; k < 12; ++k) w0[i][k] = Whh0[rr*48 + w*12 + k];
        #pragma unroll
        for (int k = 0; k < 24; ++k) {
            const int kk = w*24 + k;
            w1[i][k] = (kk < 48) ? Wih1[rr*48 + kk] : Whh1[rr*48 + kk - 48];
        }
        wih0r[i] = Wih0[rr];
    }

    // combine-role constants (threads 0..95): cell block (u_c, batch-quad bq)
    const int u_c = tid >> 1, bq = tid & 1;
    float bias0[4], bias1[4];
    if (tid < 96) {
        #pragma unroll
        for (int q = 0; q < 4; ++q) {
            bias0[q] = bih0[q*48 + u_c] + bhh0[q*48 + u_c];
            bias1[q] = bih1[q*48 + u_c] + bhh1[q*48 + u_c];
        }
    }
    // head constants (wave 0): lane = ug*8 + b8, units ug*6..+5
    const int ug = lane >> 3, b8 = lane & 7;
    float wl[6];
    #pragma unroll
    for (int j = 0; j < 6; ++j) wl[j] = Wlin[ug*6 + j];
    const float bl = blin[0];

    vf4 c0v = (vf4)0.f, c1v = (vf4)0.f;
    const int F    = fut[0];
    const int Ttot = T_OBS + F;
    const int bb0  = blockIdx.x * 8;

    float xcur = 0.f, oprev = 0.f;
    if (w == 0 && lane < 8) xcur = x[(bb0 + lane) * T_OBS];

    float* pgw = s_pg + w * PGW;
    __syncthreads();

    for (int t = 0; t < Ttot; ++t) {
        // ---- wave 0: build broadcast input (shuffles; no LDS, no race) ----
        vf4 inq[2];
        float xnext = 0.f;
        if (w == 0) {
            const float src = (t < T_OBS) ? xcur : oprev;
            #pragma unroll
            for (int qd = 0; qd < 2; ++qd)
                #pragma unroll
                for (int e = 0; e < 4; ++e)
                    inq[qd][e] = __shfl(src, qd*4 + e, 64);
            if (lane < 8 && t + 1 < T_OBS)
                xnext = x[(bb0 + lane) * T_OBS + t + 1];
        }

        // ---------- P1: layer-0 partial gates (k-quarter) ----------
        vf4 acc[3][2];
        #pragma unroll
        for (int i = 0; i < 3; ++i)
            #pragma unroll
            for (int qd = 0; qd < 2; ++qd)
                acc[i][qd] = (w == 0) ? wih0r[i] * inq[qd] : (vf4)0.f;
        {
            const float* hsrc = s_h + (w * 12) * 8;
            #pragma unroll
            for (int k = 0; k < 12; ++k) {
                vf4 hq[2];
                #pragma unroll
                for (int qd = 0; qd < 2; ++qd)
                    hq[qd] = *(const vf4*)(hsrc + k*8 + qd*4);    // uniform 16B broadcast
                #pragma unroll
                for (int i = 0; i < 3; ++i)
                    #pragma unroll
                    for (int qd = 0; qd < 2; ++qd)
                        acc[i][qd] = w0[i][k] * hq[qd] + acc[i][qd];
            }
        }
        #pragma unroll
        for (int i = 0; i < 3; ++i)
            #pragma unroll
            for (int qd = 0; qd < 2; ++qd)
                *(vf4*)(pgw + (r0 + i)*PGROW + qd*4) = acc[i][qd];
        __syncthreads();                                          // B1

        // ---------- P2: layer-0 combine ----------
        if (tid < 96) {
            vf4 g[4];
            #pragma unroll
            for (int q = 0; q < 4; ++q) {
                const float* p = s_pg + (u_c*4 + q)*PGROW + bq*4;
                vf4 s = *(const vf4*)p;
                s += *(const vf4*)(p + PGW);
                s += *(const vf4*)(p + 2*PGW);
                s += *(const vf4*)(p + 3*PGW);
                g[q] = s + bias0[q];
            }
            const vf4 ig = sigm4(g[0]), fg = sigm4(g[1]);
            const vf4 gg = tanh4(g[2]), og = sigm4(g[3]);
            c0v = fg * c0v + ig * gg;
            *(vf4*)(s_h + u_c*8 + bq*4) = og * tanh4(c0v);
        }
        __syncthreads();                                          // B2

        // ---------- P3: layer-1 partial gates (k-quarter over [h0;h1]) ----------
        #pragma unroll
        for (int i = 0; i < 3; ++i)
            #pragma unroll
            for (int qd = 0; qd < 2; ++qd)
                acc[i][qd] = (vf4)0.f;
        {
            const float* hsrc = s_h + (w * 24) * 8;
            #pragma unroll
            for (int k = 0; k < 24; ++k) {
                vf4 hq[2];
                #pragma unroll
                for (int qd = 0; qd < 2; ++qd)
                    hq[qd] = *(const vf4*)(hsrc + k*8 + qd*4);
                #pragma unroll
                for (int i = 0; i < 3; ++i)
                    #pragma unroll
                    for (int qd = 0; qd < 2; ++qd)
                        acc[i][qd] = w1[i][k] * hq[qd] + acc[i][qd];
            }
        }
        #pragma unroll
        for (int i = 0; i < 3; ++i)
            #pragma unroll
            for (int qd = 0; qd < 2; ++qd)
                *(vf4*)(pgw + (r0 + i)*PGROW + qd*4) = acc[i][qd];
        __syncthreads();                                          // B3

        // ---------- P4: layer-1 combine ----------
        if (tid < 96) {
            vf4 g[4];
            #pragma unroll
            for (int q = 0; q < 4; ++q) {
                const float* p = s_pg + (u_c*4 + q)*PGROW + bq*4;
                vf4 s = *(const vf4*)p;
                s += *(const vf4*)(p + PGW);
                s += *(const vf4*)(p + 2*PGW);
                s += *(const vf4*)(p + 3*PGW);
                g[q] = s + bias1[q];
            }
            const vf4 ig = sigm4(g[0]), fg = sigm4(g[1]);
            const vf4 gg = tanh4(g[2]), og = sigm4(g[3]);
            c1v = fg * c1v + ig * gg;
            *(vf4*)(s_h + (48 + u_c)*8 + bq*4) = og * tanh4(c1v);
        }
        __syncthreads();                                          // B4

        // ---------- P5: linear head (wave 0 only; feedback stays in-wave) ----------
        if (w == 0) {
            float s = 0.f;
            #pragma unroll
            for (int j = 0; j < 6; ++j)
                s += wl[j] * s_h[(48 + ug*6 + j)*8 + b8];
            s += __shfl_xor(s, 8, 64);
            s += __shfl_xor(s, 16, 64);
            s += __shfl_xor(s, 32, 64);          // reduce over ug; b8 preserved
            const float o = s + bl;
            if (lane < 8) out[(bb0 + lane) * Ttot + t] = o;
            oprev = o;
            xcur  = xnext;
        }
    }
}

extern "C" void kernel_launch(void* const* d_in, const int* in_sizes, int n_in,
                              void* d_out, int out_size, void* d_ws, size_t ws_size,
                              hipStream_t stream) {
    const float* x    = (const float*)d_in[0];
    const float* Wih0 = (const float*)d_in[1];
    const float* Whh0 = (const float*)d_in[2];
    const float* bih0 = (const float*)d_in[3];
    const float* bhh0 = (const float*)d_in[4];
    const float* Wih1 = (const float*)d_in[5];
    const float* Whh1 = (const float*)d_in[6];
    const float* bih1 = (const float*)d_in[7];
    const float* bhh1 = (const float*)d_in[8];
    const float* Wlin = (const float*)d_in[9];
    const float* blin = (const float*)d_in[10];
    const int*   fut  = (const int*)d_in[11];
    float* out = (float*)d_out;

    const int B = in_sizes[0] / T_OBS;    // 4096
    const int grid = B / 8;               // 512 blocks -> 2 per CU
    lstm2_kernel<<<grid, 256, 0, stream>>>(
        x, Wih0, Whh0, bih0, bhh0, Wih1, Whh1, bih1, bhh1, Wlin, blin, fut, out);
}

// Round 7
// 4881.469 us; speedup vs baseline: 13.6719x; 4.2150x over previous
//
#include <hip/hip_runtime.h>

#define T_OBS 512
#define PGROW 12            // padded row stride (floats): 8 accesses/bank for b128 (min for wave64)
#define PGW   (192*PGROW)   // per-wave partial-gate slab (8 batches/row + 4 pad)

typedef float vf4 __attribute__((ext_vector_type(4)));

// sigmoid(x) = 1/(1+2^(-x*log2 e)) ; tanh(x) = 1 - 2/(1+2^(2x*log2 e))
__device__ __forceinline__ float sigm(float v) {
    return __builtin_amdgcn_rcpf(1.f + __builtin_amdgcn_exp2f(-1.44269504089f * v));
}
__device__ __forceinline__ float tanh_f(float v) {
    return 1.f - 2.f * __builtin_amdgcn_rcpf(1.f + __builtin_amdgcn_exp2f(2.88539008178f * v));
}
__device__ __forceinline__ vf4 sigm4(vf4 v) {
    vf4 r; r[0]=sigm(v[0]); r[1]=sigm(v[1]); r[2]=sigm(v[2]); r[3]=sigm(v[3]); return r;
}
__device__ __forceinline__ vf4 tanh4(vf4 v) {
    vf4 r; r[0]=tanh_f(v[0]); r[1]=tanh_f(v[1]); r[2]=tanh_f(v[2]); r[3]=tanh_f(v[3]); return r;
}

// 256 threads = 4 waves; block cooperates on 8 batch elements (512 blocks).
// Wave w owns k-quarter of the reduction for ALL 192 gate-rows x 8 batches.
// Lane owns 3 gate-rows; weights in VGPRs: 36+72+3 = 111/lane.
// k-loops chunked into 4-k groups separated by sched_barrier(0): caps transient
// ds_read batching at 8 b128 (32 VGPRs) so the allocator never exceeds 256 —
// Round 6 (unchunked) rematerialized all weight loads from global every step
// (38 GB read-only FETCH). Biases/head-weights live in LDS, not registers.
__global__ __launch_bounds__(256, 1) void lstm2_kernel(
    const float* __restrict__ x,
    const float* __restrict__ Wih0, const float* __restrict__ Whh0,
    const float* __restrict__ bih0, const float* __restrict__ bhh0,
    const float* __restrict__ Wih1, const float* __restrict__ Whh1,
    const float* __restrict__ bih1, const float* __restrict__ bhh1,
    const float* __restrict__ Wlin, const float* __restrict__ blin,
    const int* __restrict__ fut,
    float* __restrict__ out)
{
    __shared__ __attribute__((aligned(16))) float s_pg[4*PGW];  // 36864 B
    __shared__ __attribute__((aligned(16))) float s_h[96*8];    // rows 0..47 h0, 48..95 h1
    __shared__ __attribute__((aligned(16))) float s_b0[192];    // bias L0, unit-major [u*4+q -> no: q*48+u kept as u,q]
    __shared__ __attribute__((aligned(16))) float s_b1[192];
    __shared__ __attribute__((aligned(16))) float s_wl[48];

    const int tid  = threadIdx.x;
    const int w    = tid >> 6, lane = tid & 63;
    const int r0   = lane * 3;

    for (int i = tid; i < 96*8; i += 256) s_h[i] = 0.f;
    if (tid < 192) {
        const int u = tid >> 2, q = tid & 3;        // s_b[u*4+q]
        s_b0[tid] = bih0[q*48 + u] + bhh0[q*48 + u];
        s_b1[tid] = bih1[q*48 + u] + bhh1[q*48 + u];
        if (tid < 48) s_wl[tid] = Wlin[tid];
    }

    // ---- one-time: weight quarter into registers ----
    float w0[3][12];   // Whh0[rr][w*12+k]
    float w1[3][24];   // cat[Wih1,Whh1][rr][w*24+k]
    float wih0r[3];
    #pragma unroll
    for (int i = 0; i < 3; ++i) {
        const int r = r0 + i, u = r >> 2, q = r & 3;
        const int rr = q * 48 + u;            // PyTorch row (gate-major)
        #pragma unroll
        for (int k = 0; k < 12; ++k) w0[i][k] = Whh0[rr*48 + w*12 + k];
        #pragma unroll
        for (int k = 0; k < 24; ++k) {
            const int kk = w*24 + k;
            w1[i][k] = (kk < 48) ? Wih1[rr*48 + kk] : Whh1[rr*48 + kk - 48];
        }
        wih0r[i] = Wih0[rr];
    }

    // combine-role coords (threads 0..95): cell block (u_c, batch-half bq)
    const int u_c = tid >> 1, bq = tid & 1;
    // head coords (wave 0): lane = ug*8 + b8, units ug*6..+5
    const int ug = lane >> 3, b8 = lane & 7;
    const float bl = blin[0];

    vf4 c0v = (vf4)0.f, c1v = (vf4)0.f;
    const int F    = fut[0];
    const int Ttot = T_OBS + F;
    const int bb0  = blockIdx.x * 8;

    float xcur = 0.f, oprev = 0.f;
    if (w == 0 && lane < 8) xcur = x[(bb0 + lane) * T_OBS];

    float* pgw = s_pg + w * PGW;
    __syncthreads();

    for (int t = 0; t < Ttot; ++t) {
        // ---- wave 0: build broadcast input (shuffles; no LDS, no race) ----
        vf4 inq[2];
        float xnext = 0.f;
        if (w == 0) {
            const float src = (t < T_OBS) ? xcur : oprev;
            #pragma unroll
            for (int qd = 0; qd < 2; ++qd)
                #pragma unroll
                for (int e = 0; e < 4; ++e)
                    inq[qd][e] = __shfl(src, qd*4 + e, 64);
            if (lane < 8 && t + 1 < T_OBS)
                xnext = x[(bb0 + lane) * T_OBS + t + 1];
        }

        // ---------- P1: layer-0 partial gates (k-quarter, 3 groups of 4k) ----------
        vf4 acc[3][2];
        #pragma unroll
        for (int i = 0; i < 3; ++i)
            #pragma unroll
            for (int qd = 0; qd < 2; ++qd)
                acc[i][qd] = (w == 0) ? wih0r[i] * inq[qd] : (vf4)0.f;
        {
            const float* hsrc = s_h + (w * 12) * 8;
            #pragma unroll
            for (int g = 0; g < 3; ++g) {
                vf4 hq[4][2];
                #pragma unroll
                for (int k = 0; k < 4; ++k) {
                    hq[k][0] = *(const vf4*)(hsrc + (g*4 + k)*8);
                    hq[k][1] = *(const vf4*)(hsrc + (g*4 + k)*8 + 4);
                }
                #pragma unroll
                for (int k = 0; k < 4; ++k)
                    #pragma unroll
                    for (int i = 0; i < 3; ++i)
                        #pragma unroll
                        for (int qd = 0; qd < 2; ++qd)
                            acc[i][qd] = w0[i][g*4 + k] * hq[k][qd] + acc[i][qd];
                __builtin_amdgcn_sched_barrier(0);   // cap load-batching lookahead
            }
        }
        #pragma unroll
        for (int i = 0; i < 3; ++i)
            #pragma unroll
            for (int qd = 0; qd < 2; ++qd)
                *(vf4*)(pgw + (r0 + i)*PGROW + qd*4) = acc[i][qd];
        __syncthreads();                                          // B1

        // ---------- P2: layer-0 combine ----------
        if (tid < 96) {
            vf4 g[4];
            #pragma unroll
            for (int q = 0; q < 4; ++q) {
                const float* p = s_pg + (u_c*4 + q)*PGROW + bq*4;
                vf4 s = *(const vf4*)p;
                s += *(const vf4*)(p + PGW);
                s += *(const vf4*)(p + 2*PGW);
                s += *(const vf4*)(p + 3*PGW);
                g[q] = s + s_b0[u_c*4 + q];
            }
            const vf4 ig = sigm4(g[0]), fg = sigm4(g[1]);
            const vf4 gg = tanh4(g[2]), og = sigm4(g[3]);
            c0v = fg * c0v + ig * gg;
            *(vf4*)(s_h + u_c*8 + bq*4) = og * tanh4(c0v);
        }
        __syncthreads();                                          // B2

        // ---------- P3: layer-1 partial gates (k-quarter over [h0;h1], 6 groups of 4k) ----------
        #pragma unroll
        for (int i = 0; i < 3; ++i)
            #pragma unroll
            for (int qd = 0; qd < 2; ++qd)
                acc[i][qd] = (vf4)0.f;
        {
            const float* hsrc = s_h + (w * 24) * 8;
            #pragma unroll
            for (int g = 0; g < 6; ++g) {
                vf4 hq[4][2];
                #pragma unroll
                for (int k = 0; k < 4; ++k) {
                    hq[k][0] = *(const vf4*)(hsrc + (g*4 + k)*8);
                    hq[k][1] = *(const vf4*)(hsrc + (g*4 + k)*8 + 4);
                }
                #pragma unroll
                for (int k = 0; k < 4; ++k)
                    #pragma unroll
                    for (int i = 0; i < 3; ++i)
                        #pragma unroll
                        for (int qd = 0; qd < 2; ++qd)
                            acc[i][qd] = w1[i][g*4 + k] * hq[k][qd] + acc[i][qd];
                __builtin_amdgcn_sched_barrier(0);   // cap load-batching lookahead
            }
        }
        #pragma unroll
        for (int i = 0; i < 3; ++i)
            #pragma unroll
            for (int qd = 0; qd < 2; ++qd)
                *(vf4*)(pgw + (r0 + i)*PGROW + qd*4) = acc[i][qd];
        __syncthreads();                                          // B3

        // ---------- P4: layer-1 combine ----------
        if (tid < 96) {
            vf4 g[4];
            #pragma unroll
            for (int q = 0; q < 4; ++q) {
                const float* p = s_pg + (u_c*4 + q)*PGROW + bq*4;
                vf4 s = *(const vf4*)p;
                s += *(const vf4*)(p + PGW);
                s += *(const vf4*)(p + 2*PGW);
                s += *(const vf4*)(p + 3*PGW);
                g[q] = s + s_b1[u_c*4 + q];
            }
            const vf4 ig = sigm4(g[0]), fg = sigm4(g[1]);
            const vf4 gg = tanh4(g[2]), og = sigm4(g[3]);
            c1v = fg * c1v + ig * gg;
            *(vf4*)(s_h + (48 + u_c)*8 + bq*4) = og * tanh4(c1v);
        }
        __syncthreads();                                          // B4

        // ---------- P5: linear head (wave 0 only; feedback stays in-wave) ----------
        if (w == 0) {
            float s = 0.f;
            #pragma unroll
            for (int j = 0; j < 6; ++j)
                s += s_wl[ug*6 + j] * s_h[(48 + ug*6 + j)*8 + b8];
            s += __shfl_xor(s, 8, 64);
            s += __shfl_xor(s, 16, 64);
            s += __shfl_xor(s, 32, 64);          // reduce over ug; b8 preserved
            const float o = s + bl;
            if (lane < 8) out[(bb0 + lane) * Ttot + t] = o;
            oprev = o;
            xcur  = xnext;
        }
    }
}

extern "C" void kernel_launch(void* const* d_in, const int* in_sizes, int n_in,
                              void* d_out, int out_size, void* d_ws, size_t ws_size,
                              hipStream_t stream) {
    const float* x    = (const float*)d_in[0];
    const float* Wih0 = (const float*)d_in[1];
    const float* Whh0 = (const float*)d_in[2];
    const float* bih0 = (const float*)d_in[3];
    const float* bhh0 = (const float*)d_in[4];
    const float* Wih1 = (const float*)d_in[5];
    const float* Whh1 = (const float*)d_in[6];
    const float* bih1 = (const float*)d_in[7];
    const float* bhh1 = (const float*)d_in[8];
    const float* Wlin = (const float*)d_in[9];
    const float* blin = (const float*)d_in[10];
    const int*   fut  = (const int*)d_in[11];
    float* out = (float*)d_out;

    const int B = in_sizes[0] / T_OBS;    // 4096
    const int grid = B / 8;               // 512 blocks
    lstm2_kernel<<<grid, 256, 0, stream>>>(
        x, Wih0, Whh0, bih0, bhh0, Wih1, Whh1, bih1, bhh1, Wlin, blin, fut, out);
}